// Round 16
// baseline (179.444 us; speedup 1.0000x reference)
//
#include <hip/hip_runtime.h>
#include <math.h>

#define B_DIM 2048
#define D_DIM 256
#define H1 512
#define H2 256
#define LBL 10
#define M_ROWS (B_DIM * LBL)
#define LD_A1 520  // bf16 elems; row stride 1040B -> 2-way bank alias (free)
#define WSZ1 (H1 * D_DIM)  // 131072 elems per tower, layer1 pack
#define WSZ2 (H2 * H1)     // 131072 elems per tower, layer2 pack

typedef __attribute__((ext_vector_type(8))) short frag_ab;  // 8 bf16
typedef __attribute__((ext_vector_type(4))) float frag_cd;  // 4 f32

__device__ __forceinline__ float leaky(float v) { return v > 0.f ? v : 0.01f * v; }

__device__ __forceinline__ unsigned short f2bf(float f) {  // RNE
  union { float f; unsigned int u; } v;
  v.f = f;
  unsigned int r = v.u + 0x7FFFu + ((v.u >> 16) & 1u);
  return (unsigned short)(r >> 16);
}

__device__ __forceinline__ void acc4(float4& s, const float4 a) {
  s.x += a.x; s.y += a.y; s.z += a.z; s.w += a.w;
}

// ---------- fused prologue ------------------------------------------------
// Blocks 0..511:    prefix means (EXACT R13 structure: wave = one batch,
//                   mirror-paired assignment, 8-deep unrolled running sum).
// Blocks 512..767:  fragment-order bf16 weight packs (dispatched after the
//                   prefix blocks; fill CU tail bubbles as prefix drains).
__global__ __launch_bounds__(256) void prologue_kernel(
    const float* __restrict__ x, const int* __restrict__ lens,
    unsigned short* __restrict__ hb,
    const float* __restrict__ W1a, const float* __restrict__ W1b,
    const float* __restrict__ W2a, const float* __restrict__ W2b,
    unsigned short* __restrict__ P1, unsigned short* __restrict__ P2) {
  const int bx = blockIdx.x;
  const int tid = threadIdx.x;

  if (bx < 512) {  // ---- prefix mean, one wave per batch (R13-exact)
    const int wv = tid >> 6;
    const int lane = tid & 63;
    const int idx = bx * 4 + wv;
    const int b = (idx & 1) ? (B_DIM - 1 - (idx >> 1)) : (idx >> 1);
    const int L = lens[b];
    const int Lm = L - LBL;
    const size_t ts = (size_t)(B_DIM * D_DIM / 4);
    const float4* xb =
        reinterpret_cast<const float4*>(x) + (size_t)b * (D_DIM / 4) + lane;
    float4 s0 = make_float4(0.f, 0.f, 0.f, 0.f), s1 = s0, s2 = s0, s3 = s0;
    int t = 0;
    for (; t + 8 <= Lm; t += 8) {
      float4 a0 = xb[(size_t)(t + 0) * ts], a1 = xb[(size_t)(t + 1) * ts];
      float4 a2 = xb[(size_t)(t + 2) * ts], a3 = xb[(size_t)(t + 3) * ts];
      float4 a4 = xb[(size_t)(t + 4) * ts], a5 = xb[(size_t)(t + 5) * ts];
      float4 a6 = xb[(size_t)(t + 6) * ts], a7 = xb[(size_t)(t + 7) * ts];
      acc4(s0, a0); acc4(s1, a1); acc4(s2, a2); acc4(s3, a3);
      acc4(s0, a4); acc4(s1, a5); acc4(s2, a6); acc4(s3, a7);
    }
    for (; t < Lm; ++t) acc4(s0, xb[(size_t)t * ts]);
    acc4(s0, s1); acc4(s2, s3); acc4(s0, s2);
    #pragma unroll
    for (int k = 0; k < LBL; ++k) {
      const int tt = Lm + k;
      acc4(s0, xb[(size_t)tt * ts]);
      const float inv = 1.0f / (float)(tt + 1);
      ushort4 o;
      o.x = f2bf(s0.x * inv); o.y = f2bf(s0.y * inv);
      o.z = f2bf(s0.z * inv); o.w = f2bf(s0.w * inv);
      *reinterpret_cast<ushort4*>(hb + (size_t)(b * LBL + k) * D_DIM + lane * 4) = o;
    }
    return;
  }
  if (bx < 640) {  // ---- pack1: P1[tw][cbh][ks][n][l][jj]
    const int pb = bx - 512;
    const int tw = pb >> 6;
    const int idx = (pb & 63) * 256 + tid;  // 0..16383
    const float* __restrict__ in = tw ? W1b : W1a;
    const int l = idx & 63;
    const int n = (idx >> 6) & 15;
    const int ks = (idx >> 10) & 7;
    const int cbh = idx >> 13;
    const int col = cbh * 256 + n * 16 + (l & 15);
    const int k0 = ks * 32 + (l >> 4) * 8;
    unsigned short o[8];
    #pragma unroll
    for (int jj = 0; jj < 8; ++jj)
      o[jj] = f2bf(in[(size_t)(k0 + jj) * H1 + col]);
    ushort4* dst = reinterpret_cast<ushort4*>(P1 + (size_t)tw * WSZ1 + (size_t)idx * 8);
    dst[0] = make_ushort4(o[0], o[1], o[2], o[3]);
    dst[1] = make_ushort4(o[4], o[5], o[6], o[7]);
    return;
  }
  {  // ---- pack2: P2[tw][cbh][ks][n][l][jj]  (bx 640..767)
    const int pb = bx - 640;
    const int tw = pb >> 6;
    const int idx = (pb & 63) * 256 + tid;
    const float* __restrict__ in = tw ? W2b : W2a;
    const int l = idx & 63;
    const int n = (idx >> 6) & 7;
    const int ks = (idx >> 9) & 15;
    const int cbh = idx >> 13;
    const int col = cbh * 128 + n * 16 + (l & 15);
    const int k0 = ks * 32 + (l >> 4) * 8;
    unsigned short o[8];
    #pragma unroll
    for (int jj = 0; jj < 8; ++jj)
      o[jj] = f2bf(in[(size_t)(k0 + jj) * H2 + col]);
    ushort4* dst = reinterpret_cast<ushort4*>(P2 + (size_t)tw * WSZ2 + (size_t)idx * 8);
    dst[0] = make_ushort4(o[0], o[1], o[2], o[3]);
    dst[1] = make_ushort4(o[4], o[5], o[6], o[7]);
  }
}

// ---------------- Kernel B: both towers per block, 32 rows -----------------
// Inner loops bit-identical to the measured-optimal R9/R13 tower; tw loop
// wraps them so one block produces out[] directly (no sigbuf/combine).
// 640 blocks, all co-resident at 4 blocks/CU capacity.
__global__ __launch_bounds__(256, 4) void tower_mfma(
    const unsigned short* __restrict__ hb,
    const unsigned short* __restrict__ P1,
    const unsigned short* __restrict__ P2,
    const float* __restrict__ b1a, const float* __restrict__ b2a,
    const float* __restrict__ w3a, const float* __restrict__ b3a,
    const float* __restrict__ b1b, const float* __restrict__ b2b,
    const float* __restrict__ w3b, const float* __restrict__ b3b,
    float* __restrict__ out) {
  __shared__ unsigned short A1[32][LD_A1];
  __shared__ float part[2][32];
  const int tid = threadIdx.x;
  const int l = tid & 63;
  const int w = tid >> 6;
  const int lr = l & 15;   // tile row (A) / col (B,D)
  const int lg = l >> 4;   // k-group / D row-group
  const int rb = (w & 1) * 16;
  const int cbh = w >> 1;
  const int r0 = blockIdx.x * 32;

  float prod = 0.f;

  for (int tw = 0; tw < 2; ++tw) {
    const unsigned short* __restrict__ pb1 =
        P1 + (size_t)tw * WSZ1 + (size_t)cbh * (WSZ1 / 2) + (size_t)l * 8;
    const unsigned short* __restrict__ pb2 =
        P2 + (size_t)tw * WSZ2 + (size_t)cbh * (WSZ2 / 2) + (size_t)l * 8;
    const float* __restrict__ B1 = tw ? b1b : b1a;
    const float* __restrict__ B2 = tw ? b2b : b2a;
    const float* __restrict__ W3 = tw ? w3b : w3a;
    const float* __restrict__ B3 = tw ? b3b : b3a;

    // ===== layer 1: rows r0+rb..+15, cols cbh*256..+255, K=256 =====
    frag_cd acc1[16];
    #pragma unroll
    for (int n = 0; n < 16; ++n) {
      const float bv = B1[cbh * 256 + n * 16 + lr];
      acc1[n] = (frag_cd){bv, bv, bv, bv};
    }
    const unsigned short* arow = hb + (size_t)(r0 + rb + lr) * D_DIM;
    #pragma unroll
    for (int ks = 0; ks < D_DIM / 32; ++ks) {
      const frag_ab af = *reinterpret_cast<const frag_ab*>(arow + ks * 32 + lg * 8);
      #pragma unroll
      for (int n = 0; n < 16; ++n) {
        const frag_ab bf =
            *reinterpret_cast<const frag_ab*>(pb1 + (size_t)(ks * 16 + n) * 512);
        acc1[n] = __builtin_amdgcn_mfma_f32_16x16x32_bf16(af, bf, acc1[n], 0, 0, 0);
      }
    }
    #pragma unroll
    for (int n = 0; n < 16; ++n)
      #pragma unroll
      for (int r = 0; r < 4; ++r)
        A1[rb + lg * 4 + r][cbh * 256 + n * 16 + lr] = f2bf(leaky(acc1[n][r]));
    __syncthreads();

    // ===== layer 2: rows rb..+15, cols cbh*128..+127, K=512 =====
    frag_cd acc2[8];
    #pragma unroll
    for (int n = 0; n < 8; ++n) {
      const float bv = B2[cbh * 128 + n * 16 + lr];
      acc2[n] = (frag_cd){bv, bv, bv, bv};
    }
    #pragma unroll
    for (int ks = 0; ks < H1 / 32; ++ks) {
      const frag_ab af =
          *reinterpret_cast<const frag_ab*>(&A1[rb + lr][ks * 32 + lg * 8]);
      #pragma unroll
      for (int n = 0; n < 8; ++n) {
        const frag_ab bf =
            *reinterpret_cast<const frag_ab*>(pb2 + (size_t)(ks * 8 + n) * 512);
        acc2[n] = __builtin_amdgcn_mfma_f32_16x16x32_bf16(af, bf, acc2[n], 0, 0, 0);
      }
    }

    // ===== layer 3: dot(leaky(z2), w3), reduce cols =====
    float s[4] = {0.f, 0.f, 0.f, 0.f};
    #pragma unroll
    for (int n = 0; n < 8; ++n) {
      const float w3v = W3[cbh * 128 + n * 16 + lr];
      #pragma unroll
      for (int r = 0; r < 4; ++r)
        s[r] = fmaf(leaky(acc2[n][r]), w3v, s[r]);
    }
    #pragma unroll
    for (int r = 0; r < 4; ++r) {
      s[r] += __shfl_xor(s[r], 1);
      s[r] += __shfl_xor(s[r], 2);
      s[r] += __shfl_xor(s[r], 4);
      s[r] += __shfl_xor(s[r], 8);
    }
    if (lr == 0) {
      #pragma unroll
      for (int r = 0; r < 4; ++r) part[cbh][rb + lg * 4 + r] = s[r];
    }
    __syncthreads();
    if (tid < 32) {
      const float z = leaky(part[0][tid] + part[1][tid] + B3[0]);
      const float sg = 1.f / (1.f + expf(-z));
      prod = tw ? prod * sg : sg;
    }
    __syncthreads();  // A1 / part reused by next tower
  }

  if (tid < 32) out[r0 + tid] = prod;
}

extern "C" void kernel_launch(void* const* d_in, const int* in_sizes, int n_in,
                              void* d_out, int out_size, void* d_ws, size_t ws_size,
                              hipStream_t stream) {
  (void)in_sizes; (void)n_in; (void)out_size; (void)ws_size;
  const float* x    = (const float*)d_in[0];
  const int*   lens = (const int*)d_in[1];
  // d_in[2] = label_len (hard-coded 10)
  const float* cW1 = (const float*)d_in[3];
  const float* cb1 = (const float*)d_in[4];
  const float* cW2 = (const float*)d_in[5];
  const float* cb2 = (const float*)d_in[6];
  const float* cW3 = (const float*)d_in[7];
  const float* cb3 = (const float*)d_in[8];
  const float* vW1 = (const float*)d_in[9];
  const float* vb1 = (const float*)d_in[10];
  const float* vW2 = (const float*)d_in[11];
  const float* vb2 = (const float*)d_in[12];
  const float* vW3 = (const float*)d_in[13];
  const float* vb3 = (const float*)d_in[14];
  float* out = (float*)d_out;

  // workspace layout
  unsigned short* hb = (unsigned short*)d_ws;          // 20480*256 bf16 = 10.5 MB
  unsigned short* p1 = hb + (size_t)M_ROWS * D_DIM;    // 2*131072 bf16
  unsigned short* p2 = p1 + 2 * WSZ1;                  // 2*131072 bf16

  prologue_kernel<<<768, 256, 0, stream>>>(
      x, lens, hb, cW1, vW1, cW2, vW2, p1, p2);
  tower_mfma<<<640, 256, 0, stream>>>(
      hb, p1, p2, cb1, cb2, cW3, cb3, vb1, vb2, vW3, vb3, out);
}

// Round 17
// 94.836 us; speedup vs baseline: 1.8922x; 1.8922x over previous
//
#include <hip/hip_runtime.h>
#include <math.h>

#define B_DIM 2048
#define D_DIM 256
#define H1 512
#define H2 256
#define LBL 10
#define M_ROWS (B_DIM * LBL)
#define LD_A1 520  // bf16 elems; row stride 1040B -> 2-way bank alias (free)
#define WSZ1 (H1 * D_DIM)  // 131072 elems per tower, layer1 pack
#define WSZ2 (H2 * H1)     // 131072 elems per tower, layer2 pack

typedef __attribute__((ext_vector_type(8))) short frag_ab;  // 8 bf16
typedef __attribute__((ext_vector_type(4))) float frag_cd;  // 4 f32

__device__ __forceinline__ float leaky(float v) { return v > 0.f ? v : 0.01f * v; }

__device__ __forceinline__ unsigned short f2bf(float f) {  // RNE
  union { float f; unsigned int u; } v;
  v.f = f;
  unsigned int r = v.u + 0x7FFFu + ((v.u >> 16) & 1u);
  return (unsigned short)(r >> 16);
}

__device__ __forceinline__ void acc4(float4& s, const float4 a) {
  s.x += a.x; s.y += a.y; s.z += a.z; s.w += a.w;
}

// ---------- fused prologue ------------------------------------------------
// Blocks 0..511:    prefix means (EXACT R13 structure: wave = one batch,
//                   mirror-paired assignment, 8-deep unrolled running sum).
// Blocks 512..767:  fragment-order bf16 weight packs (fill prefix-tail
//                   bubbles; tower launch waits on the whole prologue).
__global__ __launch_bounds__(256) void prologue_kernel(
    const float* __restrict__ x, const int* __restrict__ lens,
    unsigned short* __restrict__ hb,
    const float* __restrict__ W1a, const float* __restrict__ W1b,
    const float* __restrict__ W2a, const float* __restrict__ W2b,
    unsigned short* __restrict__ P1, unsigned short* __restrict__ P2) {
  const int bx = blockIdx.x;
  const int tid = threadIdx.x;

  if (bx < 512) {  // ---- prefix mean, one wave per batch (R13-exact)
    const int wv = tid >> 6;
    const int lane = tid & 63;
    const int idx = bx * 4 + wv;
    const int b = (idx & 1) ? (B_DIM - 1 - (idx >> 1)) : (idx >> 1);
    const int L = lens[b];
    const int Lm = L - LBL;
    const size_t ts = (size_t)(B_DIM * D_DIM / 4);
    const float4* xb =
        reinterpret_cast<const float4*>(x) + (size_t)b * (D_DIM / 4) + lane;
    float4 s0 = make_float4(0.f, 0.f, 0.f, 0.f), s1 = s0, s2 = s0, s3 = s0;
    int t = 0;
    for (; t + 8 <= Lm; t += 8) {
      float4 a0 = xb[(size_t)(t + 0) * ts], a1 = xb[(size_t)(t + 1) * ts];
      float4 a2 = xb[(size_t)(t + 2) * ts], a3 = xb[(size_t)(t + 3) * ts];
      float4 a4 = xb[(size_t)(t + 4) * ts], a5 = xb[(size_t)(t + 5) * ts];
      float4 a6 = xb[(size_t)(t + 6) * ts], a7 = xb[(size_t)(t + 7) * ts];
      acc4(s0, a0); acc4(s1, a1); acc4(s2, a2); acc4(s3, a3);
      acc4(s0, a4); acc4(s1, a5); acc4(s2, a6); acc4(s3, a7);
    }
    for (; t < Lm; ++t) acc4(s0, xb[(size_t)t * ts]);
    acc4(s0, s1); acc4(s2, s3); acc4(s0, s2);
    #pragma unroll
    for (int k = 0; k < LBL; ++k) {
      const int tt = Lm + k;
      acc4(s0, xb[(size_t)tt * ts]);
      const float inv = 1.0f / (float)(tt + 1);
      ushort4 o;
      o.x = f2bf(s0.x * inv); o.y = f2bf(s0.y * inv);
      o.z = f2bf(s0.z * inv); o.w = f2bf(s0.w * inv);
      *reinterpret_cast<ushort4*>(hb + (size_t)(b * LBL + k) * D_DIM + lane * 4) = o;
    }
    return;
  }
  if (bx < 640) {  // ---- pack1: P1[tw][cbh][ks][n][l][jj]
    const int pb = bx - 512;
    const int tw = pb >> 6;
    const int idx = (pb & 63) * 256 + tid;  // 0..16383
    const float* __restrict__ in = tw ? W1b : W1a;
    const int l = idx & 63;
    const int n = (idx >> 6) & 15;
    const int ks = (idx >> 10) & 7;
    const int cbh = idx >> 13;
    const int col = cbh * 256 + n * 16 + (l & 15);
    const int k0 = ks * 32 + (l >> 4) * 8;
    unsigned short o[8];
    #pragma unroll
    for (int jj = 0; jj < 8; ++jj)
      o[jj] = f2bf(in[(size_t)(k0 + jj) * H1 + col]);
    ushort4* dst = reinterpret_cast<ushort4*>(P1 + (size_t)tw * WSZ1 + (size_t)idx * 8);
    dst[0] = make_ushort4(o[0], o[1], o[2], o[3]);
    dst[1] = make_ushort4(o[4], o[5], o[6], o[7]);
    return;
  }
  {  // ---- pack2: P2[tw][cbh][ks][n][l][jj]  (bx 640..767)
    const int pb = bx - 640;
    const int tw = pb >> 6;
    const int idx = (pb & 63) * 256 + tid;
    const float* __restrict__ in = tw ? W2b : W2a;
    const int l = idx & 63;
    const int n = (idx >> 6) & 7;
    const int ks = (idx >> 9) & 15;
    const int cbh = idx >> 13;
    const int col = cbh * 128 + n * 16 + (l & 15);
    const int k0 = ks * 32 + (l >> 4) * 8;
    unsigned short o[8];
    #pragma unroll
    for (int jj = 0; jj < 8; ++jj)
      o[jj] = f2bf(in[(size_t)(k0 + jj) * H2 + col]);
    ushort4* dst = reinterpret_cast<ushort4*>(P2 + (size_t)tw * WSZ2 + (size_t)idx * 8);
    dst[0] = make_ushort4(o[0], o[1], o[2], o[3]);
    dst[1] = make_ushort4(o[4], o[5], o[6], o[7]);
  }
}

// ---------------- Kernel B: MFMA two-layer tower, 32 rows/block ------------
// EXACT R9/R13 structure (measured optimum): grid dim3(640, 2), one tower
// per blockIdx.y, 1280 independent blocks -> ~4 resident blocks/CU.
__global__ __launch_bounds__(256, 4) void tower_mfma(
    const unsigned short* __restrict__ hb,
    const unsigned short* __restrict__ P1,
    const unsigned short* __restrict__ P2,
    const float* __restrict__ b1a, const float* __restrict__ b2a,
    const float* __restrict__ w3a, const float* __restrict__ b3a,
    const float* __restrict__ b1b, const float* __restrict__ b2b,
    const float* __restrict__ w3b, const float* __restrict__ b3b,
    float* __restrict__ sigbuf) {
  __shared__ unsigned short A1[32][LD_A1];
  __shared__ float part[2][32];
  const int tid = threadIdx.x;
  const int l = tid & 63;
  const int w = tid >> 6;
  const int lr = l & 15;   // tile row (A) / col (B,D)
  const int lg = l >> 4;   // k-group / D row-group
  const int rb = (w & 1) * 16;
  const int cbh = w >> 1;
  const int r0 = blockIdx.x * 32;
  const int tw = blockIdx.y;

  const unsigned short* __restrict__ pb1 =
      P1 + (size_t)tw * WSZ1 + (size_t)cbh * (WSZ1 / 2) + (size_t)l * 8;
  const unsigned short* __restrict__ pb2 =
      P2 + (size_t)tw * WSZ2 + (size_t)cbh * (WSZ2 / 2) + (size_t)l * 8;
  const float* __restrict__ B1 = tw ? b1b : b1a;
  const float* __restrict__ B2 = tw ? b2b : b2a;
  const float* __restrict__ W3 = tw ? w3b : w3a;
  const float* __restrict__ B3 = tw ? b3b : b3a;

  // ===== layer 1: rows r0+rb..+15, cols cbh*256..+255, K=256 =====
  frag_cd acc1[16];
  #pragma unroll
  for (int n = 0; n < 16; ++n) {
    const float bv = B1[cbh * 256 + n * 16 + lr];
    acc1[n] = (frag_cd){bv, bv, bv, bv};
  }
  const unsigned short* arow = hb + (size_t)(r0 + rb + lr) * D_DIM;
  #pragma unroll
  for (int ks = 0; ks < D_DIM / 32; ++ks) {
    const frag_ab af = *reinterpret_cast<const frag_ab*>(arow + ks * 32 + lg * 8);
    #pragma unroll
    for (int n = 0; n < 16; ++n) {
      const frag_ab bf =
          *reinterpret_cast<const frag_ab*>(pb1 + (size_t)(ks * 16 + n) * 512);
      acc1[n] = __builtin_amdgcn_mfma_f32_16x16x32_bf16(af, bf, acc1[n], 0, 0, 0);
    }
  }
  #pragma unroll
  for (int n = 0; n < 16; ++n)
    #pragma unroll
    for (int r = 0; r < 4; ++r)
      A1[rb + lg * 4 + r][cbh * 256 + n * 16 + lr] = f2bf(leaky(acc1[n][r]));
  __syncthreads();

  // ===== layer 2: rows rb..+15, cols cbh*128..+127, K=512 =====
  frag_cd acc2[8];
  #pragma unroll
  for (int n = 0; n < 8; ++n) {
    const float bv = B2[cbh * 128 + n * 16 + lr];
    acc2[n] = (frag_cd){bv, bv, bv, bv};
  }
  #pragma unroll
  for (int ks = 0; ks < H1 / 32; ++ks) {
    const frag_ab af = *reinterpret_cast<const frag_ab*>(&A1[rb + lr][ks * 32 + lg * 8]);
    #pragma unroll
    for (int n = 0; n < 8; ++n) {
      const frag_ab bf =
          *reinterpret_cast<const frag_ab*>(pb2 + (size_t)(ks * 8 + n) * 512);
      acc2[n] = __builtin_amdgcn_mfma_f32_16x16x32_bf16(af, bf, acc2[n], 0, 0, 0);
    }
  }

  // ===== layer 3: dot(leaky(z2), w3), reduce cols =====
  float s[4] = {0.f, 0.f, 0.f, 0.f};
  #pragma unroll
  for (int n = 0; n < 8; ++n) {
    const float w3v = W3[cbh * 128 + n * 16 + lr];
    #pragma unroll
    for (int r = 0; r < 4; ++r)
      s[r] = fmaf(leaky(acc2[n][r]), w3v, s[r]);
  }
  #pragma unroll
  for (int r = 0; r < 4; ++r) {
    s[r] += __shfl_xor(s[r], 1);
    s[r] += __shfl_xor(s[r], 2);
    s[r] += __shfl_xor(s[r], 4);
    s[r] += __shfl_xor(s[r], 8);
  }
  if (lr == 0) {
    #pragma unroll
    for (int r = 0; r < 4; ++r) part[cbh][rb + lg * 4 + r] = s[r];
  }
  __syncthreads();
  if (tid < 32) {
    const float z = leaky(part[0][tid] + part[1][tid] + B3[0]);
    sigbuf[(size_t)tw * M_ROWS + r0 + tid] = 1.f / (1.f + expf(-z));
  }
}

// ---------------- Kernel C: out = sig_ctr * sig_cvr ----------------
__global__ __launch_bounds__(256) void combine_kernel(
    const float* __restrict__ sigbuf, float* __restrict__ out) {
  const int i = blockIdx.x * 256 + threadIdx.x;
  out[i] = sigbuf[i] * sigbuf[M_ROWS + i];
}

extern "C" void kernel_launch(void* const* d_in, const int* in_sizes, int n_in,
                              void* d_out, int out_size, void* d_ws, size_t ws_size,
                              hipStream_t stream) {
  (void)in_sizes; (void)n_in; (void)out_size; (void)ws_size;
  const float* x    = (const float*)d_in[0];
  const int*   lens = (const int*)d_in[1];
  // d_in[2] = label_len (hard-coded 10)
  const float* cW1 = (const float*)d_in[3];
  const float* cb1 = (const float*)d_in[4];
  const float* cW2 = (const float*)d_in[5];
  const float* cb2 = (const float*)d_in[6];
  const float* cW3 = (const float*)d_in[7];
  const float* cb3 = (const float*)d_in[8];
  const float* vW1 = (const float*)d_in[9];
  const float* vb1 = (const float*)d_in[10];
  const float* vW2 = (const float*)d_in[11];
  const float* vb2 = (const float*)d_in[12];
  const float* vW3 = (const float*)d_in[13];
  const float* vb3 = (const float*)d_in[14];
  float* out = (float*)d_out;

  // workspace layout
  unsigned short* hb = (unsigned short*)d_ws;          // 20480*256 bf16 = 10.5 MB
  unsigned short* p1 = hb + (size_t)M_ROWS * D_DIM;    // 2*131072 bf16
  unsigned short* p2 = p1 + 2 * WSZ1;                  // 2*131072 bf16
  float* sigbuf = (float*)(p2 + 2 * WSZ2);             // 2*20480 f32

  prologue_kernel<<<768, 256, 0, stream>>>(
      x, lens, hb, cW1, vW1, cW2, vW2, p1, p2);
  tower_mfma<<<dim3(M_ROWS / 32, 2), 256, 0, stream>>>(
      hb, p1, p2, cb1, cb2, cW3, cb3, vb1, vb2, vW3, vb3, sigbuf);
  combine_kernel<<<M_ROWS / 256, 256, 0, stream>>>(sigbuf, out);
}